// Round 10
// baseline (14.539 us; speedup 1.0000x reference)
//
#include <hip/hip_runtime.h>
#include <stdint.h>

// FSUConv2d single-cycle bipolar forward == binary XNOR-conv with threshold:
//   per tap popc(x&w) + popc(~x&~w) = 64 - popc(x^w); zero-padded tile makes
//   pad taps follow the same formula. pc = 576 - S + b_bit, S = sum popc(x^w).
//   out = (pc >= 577) = (S == 0 && b_bit) = (all 9 tap words EQUAL && b_bit).
//
// Single plain dispatch. 256 blocks (16 images x 16 uneven bands: 8 bands of
// 4 rows + 8 of 3 rows) -> every CU gets exactly one block, one round.
//   1a: pack (rpb+2)-row x halo into LDS (coalesced float4 loads).
//   1b: weight pack, COALESCED: wave loads its cout's 2304B slab with 9x256B
//       contiguous loads -> LDS float stage -> stride-9 reread (2-way bank
//       alias = free) -> ballot. (R9 read lane-strided 36B: ~36 lines per
//       load instr, ~21K TA lookups/block ~= 2us. This is 9x fewer.)
//   2:  center-tap rejection conv (R9), templated on band height.

#define NB   16
#define CIN  64
#define HH   56
#define WWD  56
#define COUT 64
#define HW   (HH * WWD)             // 3136
#define XT_COLS 58                  // 56 + 2 pad cols
#define XT_ROWS_MAX 6

__shared__ uint64_t xt[XT_ROWS_MAX * XT_COLS];  // 2784 B
__shared__ uint64_t wsh[COUT * 9];              // 4608 B
__shared__ float    wstage[8][576];             // 18432 B
__shared__ int      bflag[COUT];

template <int RPB_T>
__device__ __forceinline__ void conv_phase(float* __restrict__ out, int n, int h0) {
    int t = threadIdx.x;
    if (t >= 448) return;
    int q   = t % 14;
    int cp  = t / 14;                 // cout pair index
    int c0  = q * 4;
    int co0 = cp * 2;

    // center rows 1..RPB_T (16B aligned: 58*rr + 4q is even)
    uint64_t rc[RPB_T][6];
#pragma unroll
    for (int rr = 0; rr < RPB_T; ++rr) {
        const ulonglong2* p = (const ulonglong2*)&xt[(rr + 1) * XT_COLS + c0];
        ulonglong2 a = p[0], b = p[1], cc = p[2];
        rc[rr][0] = a.x; rc[rr][1] = a.y; rc[rr][2] = b.x;
        rc[rr][3] = b.y; rc[rr][4] = cc.x; rc[rr][5] = cc.y;
    }
    uint64_t wc0 = wsh[co0 * 9 + 4];
    uint64_t wc1 = wsh[(co0 + 1) * 9 + 4];
    int bb0 = bflag[co0], bb1 = bflag[co0 + 1];

    int hit0 = 0, hit1 = 0;
#pragma unroll
    for (int orow = 0; orow < RPB_T; ++orow)
#pragma unroll
        for (int o = 0; o < 4; ++o) {
            uint64_t cw = rc[orow][o + 1];
            hit0 |= (cw == wc0);
            hit1 |= (cw == wc1);
        }

    float* ob0 = out + ((size_t)n * COUT + co0) * HW + (size_t)h0 * WWD + c0;
    float* ob1 = ob0 + HW;

    if (!((hit0 & bb0) | (hit1 & bb1))) {
        float4 z = make_float4(0.0f, 0.0f, 0.0f, 0.0f);
#pragma unroll
        for (int orow = 0; orow < RPB_T; ++orow) {
            *(float4*)(ob0 + (size_t)orow * WWD) = z;
            *(float4*)(ob1 + (size_t)orow * WWD) = z;
        }
        return;
    }

    // cold full path: halo rows 0 and RPB_T+1, evaluate all 9 taps exactly
    uint64_t rA[RPB_T + 2][6];
#pragma unroll
    for (int c = 0; c < 6; ++c) {
        rA[0][c]         = xt[c0 + c];
        rA[RPB_T + 1][c] = xt[(RPB_T + 1) * XT_COLS + c0 + c];
    }
#pragma unroll
    for (int rr = 0; rr < RPB_T; ++rr)
#pragma unroll
        for (int c = 0; c < 6; ++c) rA[rr + 1][c] = rc[rr][c];

#pragma unroll
    for (int ci = 0; ci < 2; ++ci) {
        int co = co0 + ci;
        int bb = ci ? bb1 : bb0;
        float* ob = ci ? ob1 : ob0;
        uint64_t wp[9];
#pragma unroll
        for (int k = 0; k < 9; ++k) wp[k] = wsh[co * 9 + k];
#pragma unroll
        for (int orow = 0; orow < RPB_T; ++orow) {
            float v[4];
#pragma unroll
            for (int o = 0; o < 4; ++o) {
                int e = bb;
#pragma unroll
                for (int kh = 0; kh < 3; ++kh)
#pragma unroll
                    for (int kw = 0; kw < 3; ++kw)
                        e &= (rA[orow + kh][o + kw] == wp[kh * 3 + kw]);
                v[o] = e ? 1.0f : 0.0f;
            }
            *(float4*)(ob + (size_t)orow * WWD) = make_float4(v[0], v[1], v[2], v[3]);
        }
    }
}

__global__ __launch_bounds__(512) void fused_conv(const float* __restrict__ x,
                                                  const float* __restrict__ w,
                                                  const float* __restrict__ bias,
                                                  float* __restrict__ out) {
    int n    = blockIdx.x >> 4;
    int band = blockIdx.x & 15;
    int rpb  = (band < 8) ? 4 : 3;
    int h0   = (band < 8) ? band * 4 : 32 + (band - 8) * 3;
    int xrows = rpb + 2;

    // ---- phase 1a: pack x halo rows h0-1 .. h0+rpb into padded LDS tile
    int nptask = xrows * 112;                  // (row, cg8, px-quad) tasks
    for (int t = threadIdx.x; t < nptask + 2 * xrows; t += 512) {
        if (t < nptask) {
            int row = t / 112;
            int rem = t - row * 112;
            int cg8 = rem / 14;
            int pg  = rem - cg8 * 14;
            int gh  = h0 - 1 + row;
            int pc0 = pg * 4;
            uint32_t b0 = 0, b1 = 0, b2 = 0, b3 = 0;
            if (gh >= 0 && gh < HH) {
                const float* xp = x + (size_t)n * CIN * HW + (size_t)(cg8 * 8) * HW
                                    + (size_t)gh * WWD + pc0;
#pragma unroll
                for (int i = 0; i < 8; ++i) {
                    float4 v = *(const float4*)(xp + (size_t)i * HW);
                    b0 |= (uint32_t)(v.x != 0.0f) << i;
                    b1 |= (uint32_t)(v.y != 0.0f) << i;
                    b2 |= (uint32_t)(v.z != 0.0f) << i;
                    b3 |= (uint32_t)(v.w != 0.0f) << i;
                }
            }
            uint8_t* xb = (uint8_t*)xt;
            int base = (row * XT_COLS + 1 + pc0) * 8 + cg8;
            xb[base]      = (uint8_t)b0;
            xb[base + 8]  = (uint8_t)b1;
            xb[base + 16] = (uint8_t)b2;
            xb[base + 24] = (uint8_t)b3;
        } else {
            int i = t - nptask;                // zero the pad-column words
            int row = i >> 1, col = (i & 1) ? (XT_COLS - 1) : 0;
            xt[row * XT_COLS + col] = 0ull;
        }
    }

    // ---- phase 1b: coalesced weight pack via LDS transpose stage
    {
        int wid  = threadIdx.x >> 6;
        int lane = threadIdx.x & 63;
        float* st = wstage[wid];
#pragma unroll
        for (int i = 0; i < 8; ++i) {
            int co = wid * 8 + i;
            const float* ws = w + (size_t)co * (CIN * 9);
#pragma unroll
            for (int k = 0; k < 9; ++k) st[k * 64 + lane] = ws[k * 64 + lane];
            // same-wave write->read: compiler inserts lgkmcnt wait (aliasing)
            float f0 = st[lane * 9 + 0], f1 = st[lane * 9 + 1], f2 = st[lane * 9 + 2],
                  f3 = st[lane * 9 + 3], f4 = st[lane * 9 + 4], f5 = st[lane * 9 + 5],
                  f6 = st[lane * 9 + 6], f7 = st[lane * 9 + 7], f8 = st[lane * 9 + 8];
            uint64_t q0 = __ballot(f0 > 0.0f), q1 = __ballot(f1 > 0.0f),
                     q2 = __ballot(f2 > 0.0f), q3 = __ballot(f3 > 0.0f),
                     q4 = __ballot(f4 > 0.0f), q5 = __ballot(f5 > 0.0f),
                     q6 = __ballot(f6 > 0.0f), q7 = __ballot(f7 > 0.0f),
                     q8 = __ballot(f8 > 0.0f);
            if (lane == 0) {
                uint64_t* d = &wsh[co * 9];
                d[0] = q0; d[1] = q1; d[2] = q2; d[3] = q3; d[4] = q4;
                d[5] = q5; d[6] = q6; d[7] = q7; d[8] = q8;
            }
        }
    }
    if (threadIdx.x < COUT) bflag[threadIdx.x] = bias[threadIdx.x] > 0.0f;
    __syncthreads();

    // ---- phase 2: center-tap rejection conv
    if (rpb == 4) conv_phase<4>(out, n, h0);
    else          conv_phase<3>(out, n, h0);
}

extern "C" void kernel_launch(void* const* d_in, const int* in_sizes, int n_in,
                              void* d_out, int out_size, void* d_ws, size_t ws_size,
                              hipStream_t stream) {
    const float* x    = (const float*)d_in[0];
    const float* wgt  = (const float*)d_in[1];
    const float* bias = (const float*)d_in[2];
    float* out = (float*)d_out;

    fused_conv<<<NB * 16, 512, 0, stream>>>(x, wgt, bias, out);
}

// Round 11
// 12.970 us; speedup vs baseline: 1.1210x; 1.1210x over previous
//
#include <hip/hip_runtime.h>
#include <stdint.h>

// FSUConv2d single-cycle bipolar forward == binary XNOR-conv with threshold:
//   per tap popc(x&w) + popc(~x&~w) = 64 - popc(x^w); zero-padded tile makes
//   pad taps follow the same formula. pc = 576 - S + b_bit, S = sum popc(x^w).
//   out = (pc >= 577) = (S == 0 && b_bit) = (all 9 tap words EQUAL && b_bit).
//
// Single plain dispatch, 224 blocks (R10's 256-block uneven split regressed:
// more halo redundancy + 14% more per-block weight packing). Block =
// (n, 4-row band), 512 threads.
//   1a: pack 6-row x halo into LDS (coalesced float4 loads).
//   1b: pack ONLY the 64 center-tap weight words (8 loads/wave, was 72) --
//       the hot path never reads the other 512 words.
//   2a: center-tap rejection test; no-hit threads store zeros immediately.
//   2b: (cold, wave-uniform) lazily ballot-pack full 9 words for flagged
//       couts only -- on real bitstream data this never runs (P~2^-64).
//   2c: (cold, per-thread) full 9-tap equality eval for hit tiles.

#define NB   16
#define CIN  64
#define HH   56
#define WWD  56
#define COUT 64
#define HW   (HH * WWD)             // 3136
#define RPB  4                      // output rows per block
#define BANDS (HH / RPB)            // 14
#define NBLOCKS (NB * BANDS)        // 224
#define XT_ROWS (RPB + 2)           // 6 padded input rows
#define XT_COLS 58                  // 56 + 2 pad cols
#define XT_WORDS (XT_ROWS * XT_COLS)  // 348
#define NPTASK (XT_ROWS * 8 * 14)   // 672 pack tasks
#define NPADW  (XT_ROWS * 2)        // 12 pad-column words

__global__ __launch_bounds__(512) void fused_conv(const float* __restrict__ x,
                                                  const float* __restrict__ w,
                                                  const float* __restrict__ bias,
                                                  float* __restrict__ out) {
    __shared__ uint64_t xt[XT_WORDS];     // 2784 B padded bit tile
    __shared__ uint64_t wsh[COUT * 9];    // full weight words (lazy)
    __shared__ uint64_t wcen[COUT];       // center-tap words (hot)
    __shared__ int bflag[COUT];
    __shared__ int needflag[COUT];

    int n    = blockIdx.x / BANDS;
    int band = blockIdx.x % BANDS;
    int h0   = band * RPB;

    // ---- phase 1a: pack x halo rows h0-1 .. h0+RPB into padded LDS tile
    for (int t = threadIdx.x; t < NPTASK + NPADW; t += 512) {
        if (t < NPTASK) {
            int row = t / 112;            // 0..5   (gh = h0-1+row)
            int rem = t - row * 112;
            int cg8 = rem / 14;           // 0..7   channels [8*cg8, 8*cg8+8)
            int pg  = rem - cg8 * 14;     // 0..13  pixel cols [4*pg, 4*pg+4)
            int gh  = h0 - 1 + row;
            int pc0 = pg * 4;
            uint32_t b0 = 0, b1 = 0, b2 = 0, b3 = 0;
            if (gh >= 0 && gh < HH) {
                const float* xp = x + (size_t)n * CIN * HW + (size_t)(cg8 * 8) * HW
                                    + (size_t)gh * WWD + pc0;
#pragma unroll
                for (int i = 0; i < 8; ++i) {
                    float4 v = *(const float4*)(xp + (size_t)i * HW);
                    b0 |= (uint32_t)(v.x != 0.0f) << i;
                    b1 |= (uint32_t)(v.y != 0.0f) << i;
                    b2 |= (uint32_t)(v.z != 0.0f) << i;
                    b3 |= (uint32_t)(v.w != 0.0f) << i;
                }
            }
            uint8_t* xb = (uint8_t*)xt;
            int base = (row * XT_COLS + 1 + pc0) * 8 + cg8;
            xb[base]      = (uint8_t)b0;
            xb[base + 8]  = (uint8_t)b1;
            xb[base + 16] = (uint8_t)b2;
            xb[base + 24] = (uint8_t)b3;
        } else {
            int i = t - NPTASK;           // zero the pad-column words
            int row = i >> 1, col = (i & 1) ? (XT_COLS - 1) : 0;
            xt[row * XT_COLS + col] = 0ull;
        }
    }

    // ---- phase 1b: center-tap-only ballot weight pack (8 loads per wave)
    int wid  = threadIdx.x >> 6;
    int lane = threadIdx.x & 63;
#pragma unroll
    for (int i = 0; i < 8; ++i) {
        int co = wid * 8 + i;
        float f = w[(size_t)co * (CIN * 9) + (size_t)lane * 9 + 4];
        uint64_t qb = __ballot(f > 0.0f);
        if (lane == 0) wcen[co] = qb;
    }
    if (threadIdx.x < COUT) {
        bflag[threadIdx.x]    = bias[threadIdx.x] > 0.0f;
        needflag[threadIdx.x] = 0;
    }
    __syncthreads();

    // ---- phase 2a: center-tap rejection; zero-store on the (hot) miss path
    int t = threadIdx.x;
    bool active = t < 448;
    bool need   = false;
    uint64_t rc[RPB][6];
    int c0 = 0, co0 = 0, bb0 = 0, bb1 = 0;
    float *ob0 = nullptr, *ob1 = nullptr;
    if (active) {
        int q  = t % 14;
        int cp = t / 14;                  // cout pair index
        c0  = q * 4;
        co0 = cp * 2;
#pragma unroll
        for (int rr = 0; rr < RPB; ++rr) {
            const ulonglong2* p = (const ulonglong2*)&xt[(rr + 1) * XT_COLS + c0];
            ulonglong2 a = p[0], b = p[1], cc = p[2];
            rc[rr][0] = a.x; rc[rr][1] = a.y; rc[rr][2] = b.x;
            rc[rr][3] = b.y; rc[rr][4] = cc.x; rc[rr][5] = cc.y;
        }
        uint64_t wc0 = wcen[co0];
        uint64_t wc1 = wcen[co0 + 1];
        bb0 = bflag[co0]; bb1 = bflag[co0 + 1];

        int hit0 = 0, hit1 = 0;
#pragma unroll
        for (int orow = 0; orow < RPB; ++orow)
#pragma unroll
            for (int o = 0; o < 4; ++o) {
                uint64_t cw = rc[orow][o + 1];
                hit0 |= (cw == wc0);
                hit1 |= (cw == wc1);
            }

        ob0 = out + ((size_t)n * COUT + co0) * HW + (size_t)h0 * WWD + c0;
        ob1 = ob0 + HW;
        need = ((hit0 & bb0) | (hit1 & bb1)) != 0;
        if (need) {                       // benign race: only ever writes 1
            needflag[co0]     = 1;
            needflag[co0 + 1] = 1;
        } else {
            float4 z = make_float4(0.0f, 0.0f, 0.0f, 0.0f);
#pragma unroll
            for (int orow = 0; orow < RPB; ++orow) {
                *(float4*)(ob0 + (size_t)orow * WWD) = z;
                *(float4*)(ob1 + (size_t)orow * WWD) = z;
            }
        }
    }
    __syncthreads();

    // ---- phase 2b (cold): lazily pack full 9 words for flagged couts.
    //      needflag[] is wave-uniform -> whole wave enters, ballot is safe.
#pragma unroll
    for (int i = 0; i < 8; ++i) {
        int co = wid * 8 + i;
        if (needflag[co]) {
            const float* ws = w + (size_t)co * (CIN * 9) + (size_t)lane * 9;
#pragma unroll
            for (int k = 0; k < 9; ++k) {
                uint64_t qb = __ballot(ws[k] > 0.0f);
                if (lane == 0) wsh[co * 9 + k] = qb;
            }
        }
    }
    __syncthreads();

    // ---- phase 2c (cold): full 9-tap equality eval for hit tiles
    if (need) {
        uint64_t rA[XT_ROWS][6];
#pragma unroll
        for (int c = 0; c < 6; ++c) {
            rA[0][c]           = xt[c0 + c];
            rA[XT_ROWS - 1][c] = xt[(XT_ROWS - 1) * XT_COLS + c0 + c];
        }
#pragma unroll
        for (int rr = 0; rr < RPB; ++rr)
#pragma unroll
            for (int c = 0; c < 6; ++c) rA[rr + 1][c] = rc[rr][c];

#pragma unroll
        for (int ci = 0; ci < 2; ++ci) {
            int co = co0 + ci;
            int bb = ci ? bb1 : bb0;
            float* ob = ci ? ob1 : ob0;
            uint64_t wp[9];
#pragma unroll
            for (int k = 0; k < 9; ++k) wp[k] = wsh[co * 9 + k];
#pragma unroll
            for (int orow = 0; orow < RPB; ++orow) {
                float v[4];
#pragma unroll
                for (int o = 0; o < 4; ++o) {
                    int e = bb;
#pragma unroll
                    for (int kh = 0; kh < 3; ++kh)
#pragma unroll
                        for (int kw = 0; kw < 3; ++kw)
                            e &= (rA[orow + kh][o + kw] == wp[kh * 3 + kw]);
                    v[o] = e ? 1.0f : 0.0f;
                }
                *(float4*)(ob + (size_t)orow * WWD) = make_float4(v[0], v[1], v[2], v[3]);
            }
        }
    }
}

extern "C" void kernel_launch(void* const* d_in, const int* in_sizes, int n_in,
                              void* d_out, int out_size, void* d_ws, size_t ws_size,
                              hipStream_t stream) {
    const float* x    = (const float*)d_in[0];
    const float* wgt  = (const float*)d_in[1];
    const float* bias = (const float*)d_in[2];
    float* out = (float*)d_out;

    fused_conv<<<NBLOCKS, 512, 0, stream>>>(x, wgt, bias, out);
}

// Round 12
// 12.756 us; speedup vs baseline: 1.1398x; 1.0168x over previous
//
#include <hip/hip_runtime.h>
#include <stdint.h>

// FSUConv2d single-cycle bipolar forward == binary XNOR-conv with threshold:
//   per tap popc(x&w) + popc(~x&~w) = 64 - popc(x^w); zero-padded tile makes
//   pad taps follow the same formula. pc = 576 - S + b_bit, S = sum popc(x^w).
//   out = (pc >= 577) = (S == 0 && b_bit) = (all 9 tap words EQUAL && b_bit).
//
// Single plain dispatch, 224 blocks x 1024 threads (16 waves/CU -- R11 had 8;
// phase 1a is an HBM-read latency game, 2x waves = 2x loads in flight).
//   1a: pack 6-row x halo into LDS (coalesced float4 loads, <=1 task/thread).
//   1b: pack ONLY the 64 center-tap weight words (hot path needs just these).
//   2a: center-tap rejection; 896 threads, 1 cout x 4x4 tile each;
//       miss -> immediate zero store (the hot path on bitstream data).
//   2b: (cold) lazy ballot-pack of full 9 words for flagged couts.
//   2c: (cold) exact 9-tap equality eval for hit tiles.

#define NB   16
#define CIN  64
#define HH   56
#define WWD  56
#define COUT 64
#define HW   (HH * WWD)             // 3136
#define RPB  4                      // output rows per block
#define BANDS (HH / RPB)            // 14
#define NBLOCKS (NB * BANDS)        // 224
#define XT_ROWS (RPB + 2)           // 6 padded input rows
#define XT_COLS 58                  // 56 + 2 pad cols
#define XT_WORDS (XT_ROWS * XT_COLS)  // 348
#define NPTASK (XT_ROWS * 8 * 14)   // 672 pack tasks
#define NPADW  (XT_ROWS * 2)        // 12 pad-column words
#define NTHREADS 1024

__global__ __launch_bounds__(NTHREADS) void fused_conv(const float* __restrict__ x,
                                                       const float* __restrict__ w,
                                                       const float* __restrict__ bias,
                                                       float* __restrict__ out) {
    __shared__ uint64_t xt[XT_WORDS];     // 2784 B padded bit tile
    __shared__ uint64_t wsh[COUT * 9];    // full weight words (lazy)
    __shared__ uint64_t wcen[COUT];       // center-tap words (hot)
    __shared__ int bflag[COUT];
    __shared__ int needflag[COUT];

    int n    = blockIdx.x / BANDS;
    int band = blockIdx.x % BANDS;
    int h0   = band * RPB;

    int tid  = threadIdx.x;
    int wid  = tid >> 6;                  // 0..15
    int lane = tid & 63;

    // ---- phase 1a: pack x halo rows h0-1 .. h0+RPB into padded LDS tile
    if (tid < NPTASK) {
        int row = tid / 112;              // 0..5   (gh = h0-1+row)
        int rem = tid - row * 112;
        int cg8 = rem / 14;               // 0..7   channels [8*cg8, 8*cg8+8)
        int pg  = rem - cg8 * 14;         // 0..13  pixel cols [4*pg, 4*pg+4)
        int gh  = h0 - 1 + row;
        int pc0 = pg * 4;
        uint32_t b0 = 0, b1 = 0, b2 = 0, b3 = 0;
        if (gh >= 0 && gh < HH) {
            const float* xp = x + (size_t)n * CIN * HW + (size_t)(cg8 * 8) * HW
                                + (size_t)gh * WWD + pc0;
#pragma unroll
            for (int i = 0; i < 8; ++i) {
                float4 v = *(const float4*)(xp + (size_t)i * HW);
                b0 |= (uint32_t)(v.x != 0.0f) << i;
                b1 |= (uint32_t)(v.y != 0.0f) << i;
                b2 |= (uint32_t)(v.z != 0.0f) << i;
                b3 |= (uint32_t)(v.w != 0.0f) << i;
            }
        }
        uint8_t* xb = (uint8_t*)xt;
        int base = (row * XT_COLS + 1 + pc0) * 8 + cg8;
        xb[base]      = (uint8_t)b0;
        xb[base + 8]  = (uint8_t)b1;
        xb[base + 16] = (uint8_t)b2;
        xb[base + 24] = (uint8_t)b3;
    } else if (tid < NPTASK + NPADW) {
        int i = tid - NPTASK;             // zero the pad-column words
        int row = i >> 1, col = (i & 1) ? (XT_COLS - 1) : 0;
        xt[row * XT_COLS + col] = 0ull;
    }

    // ---- phase 1b: center-tap-only ballot weight pack (4 couts per wave)
#pragma unroll
    for (int i = 0; i < 4; ++i) {
        int co = wid * 4 + i;
        float f = w[(size_t)co * (CIN * 9) + (size_t)lane * 9 + 4];
        uint64_t qb = __ballot(f > 0.0f);
        if (lane == 0) wcen[co] = qb;
    }
    if (tid < COUT) {
        bflag[tid]    = bias[tid] > 0.0f;
        needflag[tid] = 0;
    }
    __syncthreads();

    // ---- phase 2a: center-tap rejection; 896 threads, 1 cout x 4x4 each
    bool active = tid < 896;
    bool need   = false;
    uint64_t rc[RPB][6];
    int c0 = 0, co = 0, bb = 0;
    float* ob = nullptr;
    if (active) {
        co = tid / 14;
        int q = tid - co * 14;
        c0 = q * 4;
#pragma unroll
        for (int rr = 0; rr < RPB; ++rr) {
            const ulonglong2* p = (const ulonglong2*)&xt[(rr + 1) * XT_COLS + c0];
            ulonglong2 a = p[0], b = p[1], cc = p[2];
            rc[rr][0] = a.x; rc[rr][1] = a.y; rc[rr][2] = b.x;
            rc[rr][3] = b.y; rc[rr][4] = cc.x; rc[rr][5] = cc.y;
        }
        uint64_t wc = wcen[co];
        bb = bflag[co];

        int hit = 0;
#pragma unroll
        for (int orow = 0; orow < RPB; ++orow)
#pragma unroll
            for (int o = 0; o < 4; ++o) hit |= (rc[orow][o + 1] == wc);

        ob = out + ((size_t)n * COUT + co) * HW + (size_t)h0 * WWD + c0;
        need = (hit & bb) != 0;
        if (need) {
            needflag[co] = 1;             // benign race: only ever writes 1
        } else {
            float4 z = make_float4(0.0f, 0.0f, 0.0f, 0.0f);
#pragma unroll
            for (int orow = 0; orow < RPB; ++orow)
                *(float4*)(ob + (size_t)orow * WWD) = z;
        }
    }
    __syncthreads();

    // ---- phase 2b (cold): lazily pack full 9 words for flagged couts.
    //      needflag[] is wave-uniform -> whole wave enters, ballot is safe.
#pragma unroll
    for (int i = 0; i < 4; ++i) {
        int cw = wid * 4 + i;
        if (needflag[cw]) {
            const float* ws = w + (size_t)cw * (CIN * 9) + (size_t)lane * 9;
#pragma unroll
            for (int k = 0; k < 9; ++k) {
                uint64_t qb = __ballot(ws[k] > 0.0f);
                if (lane == 0) wsh[cw * 9 + k] = qb;
            }
        }
    }
    __syncthreads();

    // ---- phase 2c (cold): full 9-tap equality eval for hit tiles
    if (need) {
        uint64_t rA[XT_ROWS][6];
#pragma unroll
        for (int c = 0; c < 6; ++c) {
            rA[0][c]           = xt[c0 + c];
            rA[XT_ROWS - 1][c] = xt[(XT_ROWS - 1) * XT_COLS + c0 + c];
        }
#pragma unroll
        for (int rr = 0; rr < RPB; ++rr)
#pragma unroll
            for (int c = 0; c < 6; ++c) rA[rr + 1][c] = rc[rr][c];

        uint64_t wp[9];
#pragma unroll
        for (int k = 0; k < 9; ++k) wp[k] = wsh[co * 9 + k];
#pragma unroll
        for (int orow = 0; orow < RPB; ++orow) {
            float v[4];
#pragma unroll
            for (int o = 0; o < 4; ++o) {
                int e = bb;
#pragma unroll
                for (int kh = 0; kh < 3; ++kh)
#pragma unroll
                    for (int kw = 0; kw < 3; ++kw)
                        e &= (rA[orow + kh][o + kw] == wp[kh * 3 + kw]);
                v[o] = e ? 1.0f : 0.0f;
            }
            *(float4*)(ob + (size_t)orow * WWD) = make_float4(v[0], v[1], v[2], v[3]);
        }
    }
}

extern "C" void kernel_launch(void* const* d_in, const int* in_sizes, int n_in,
                              void* d_out, int out_size, void* d_ws, size_t ws_size,
                              hipStream_t stream) {
    const float* x    = (const float*)d_in[0];
    const float* wgt  = (const float*)d_in[1];
    const float* bias = (const float*)d_in[2];
    float* out = (float*)d_out;

    fused_conv<<<NBLOCKS, NTHREADS, 0, stream>>>(x, wgt, bias, out);
}

// Round 13
// 11.675 us; speedup vs baseline: 1.2454x; 1.0926x over previous
//
#include <hip/hip_runtime.h>
#include <stdint.h>

// FSUConv2d single-cycle bipolar forward == binary XNOR-conv with threshold:
//   per tap popc(x&w) + popc(~x&~w) = 64 - popc(x^w); zero-padded tile makes
//   pad taps follow the same formula. pc = 576 - S + b_bit, S = sum popc(x^w).
//   out = (pc >= 577) = (S == 0 && b_bit) = (all 9 tap words EQUAL && b_bit).
//
// Single dispatch, 224 blocks x 1024 threads, PIPELINED within the block so
// HBM stores overlap HBM loads (R12's phases were fully serial):
//   A: pack xt rows 0..3 + center-tap weight words + bias flags.   [read]
//   B: tids 0..447 conv out rows h0,h0+1 (reject -> zero stores)   [write]
//      tids 448..1023 pack xt rows 4..5 concurrently.              [read]
//   C: conv out rows h0+2,h0+3.                                    [write]
//   D: (cold, P~2^-64/word) lazy full weight pack + exact 9-tap eval.

#define NB   16
#define CIN  64
#define HH   56
#define WWD  56
#define COUT 64
#define HW   (HH * WWD)             // 3136
#define RPB  4
#define BANDS (HH / RPB)            // 14
#define NBLOCKS (NB * BANDS)        // 224
#define XT_COLS 58
#define NTHREADS 1024

__global__ __launch_bounds__(NTHREADS) void fused_conv(const float* __restrict__ x,
                                                       const float* __restrict__ w,
                                                       const float* __restrict__ bias,
                                                       float* __restrict__ out) {
    __shared__ uint64_t xt[6 * XT_COLS];
    __shared__ uint64_t wsh[COUT * 9];    // full weight words (lazy)
    __shared__ uint64_t wcen[COUT];       // center-tap words (hot)
    __shared__ int bflag[COUT];
    __shared__ int needflag[COUT];

    int n    = blockIdx.x / BANDS;
    int band = blockIdx.x % BANDS;
    int h0   = band * RPB;
    int tid  = threadIdx.x;
    int wid  = tid >> 6;
    int lane = tid & 63;

    auto pack_task = [&](int row, int rem) {
        int cg8 = rem / 14;
        int pg  = rem - cg8 * 14;
        int gh  = h0 - 1 + row;
        int pc0 = pg * 4;
        uint32_t b0 = 0, b1 = 0, b2 = 0, b3 = 0;
        if (gh >= 0 && gh < HH) {
            const float* xp = x + (size_t)n * CIN * HW + (size_t)(cg8 * 8) * HW
                                + (size_t)gh * WWD + pc0;
#pragma unroll
            for (int i = 0; i < 8; ++i) {
                float4 v = *(const float4*)(xp + (size_t)i * HW);
                b0 |= (uint32_t)(v.x != 0.0f) << i;
                b1 |= (uint32_t)(v.y != 0.0f) << i;
                b2 |= (uint32_t)(v.z != 0.0f) << i;
                b3 |= (uint32_t)(v.w != 0.0f) << i;
            }
        }
        uint8_t* xb = (uint8_t*)xt;
        int base = (row * XT_COLS + 1 + pc0) * 8 + cg8;
        xb[base]      = (uint8_t)b0;
        xb[base + 8]  = (uint8_t)b1;
        xb[base + 16] = (uint8_t)b2;
        xb[base + 24] = (uint8_t)b3;
    };

    // ---- phase A: pack xt rows 0..3; pads rows 0..3; wcen; bias flags
    if (tid < 448) {
        pack_task(tid / 112, tid % 112);
    } else if (tid < 456) {
        int i = tid - 448;
        xt[(i >> 1) * XT_COLS + ((i & 1) ? XT_COLS - 1 : 0)] = 0ull;
    }
#pragma unroll
    for (int i = 0; i < 4; ++i) {
        int co = wid * 4 + i;
        float f = w[(size_t)co * (CIN * 9) + (size_t)lane * 9 + 4];
        uint64_t qb = __ballot(f > 0.0f);
        if (lane == 0) wcen[co] = qb;
    }
    if (tid < COUT) {
        bflag[tid]    = bias[tid] > 0.0f;
        needflag[tid] = 0;
    }
    __syncthreads();

    bool isconv = tid < 448;
    int c0 = 0, co0 = 0, bb0 = 0, bb1 = 0;
    uint64_t wc0 = 0, wc1 = 0;
    if (isconv) {
        int q  = tid % 14;
        int cp = tid / 14;
        c0  = q * 4;
        co0 = cp * 2;
        wc0 = wcen[co0];
        wc1 = wcen[co0 + 1];
        bb0 = bflag[co0];
        bb1 = bflag[co0 + 1];
    }

    // hot chunk: center-tap reject for out rows h0+2*chunk, h0+2*chunk+1
    auto chunk_hot = [&](int chunk) -> bool {
        uint64_t rc2[2][6];
#pragma unroll
        for (int r = 0; r < 2; ++r) {
            const ulonglong2* p =
                (const ulonglong2*)&xt[(2 * chunk + 1 + r) * XT_COLS + c0];
            ulonglong2 a = p[0], b = p[1], cc = p[2];
            rc2[r][0] = a.x; rc2[r][1] = a.y; rc2[r][2] = b.x;
            rc2[r][3] = b.y; rc2[r][4] = cc.x; rc2[r][5] = cc.y;
        }
        int hit0 = 0, hit1 = 0;
#pragma unroll
        for (int r = 0; r < 2; ++r)
#pragma unroll
            for (int o = 0; o < 4; ++o) {
                uint64_t cw = rc2[r][o + 1];
                hit0 |= (cw == wc0);
                hit1 |= (cw == wc1);
            }
        bool need = ((hit0 & bb0) | (hit1 & bb1)) != 0;
        float* ob0 = out + ((size_t)n * COUT + co0) * HW
                         + (size_t)(h0 + 2 * chunk) * WWD + c0;
        if (need) {                       // benign race: only ever writes 1
            needflag[co0]     = 1;
            needflag[co0 + 1] = 1;
        } else {
            float4 z = make_float4(0.0f, 0.0f, 0.0f, 0.0f);
            *(float4*)ob0              = z;
            *(float4*)(ob0 + WWD)      = z;
            *(float4*)(ob0 + HW)       = z;
            *(float4*)(ob0 + HW + WWD) = z;
        }
        return need;
    };

    // ---- phase B: conv chunk 0 (stores) || pack xt rows 4..5 (loads)
    bool need_b = false, need_c = false;
    if (isconv) {
        need_b = chunk_hot(0);
    } else {
        int t2 = tid - 448;
        if (t2 < 224) {
            pack_task(4 + t2 / 112, t2 % 112);
        } else if (t2 < 228) {
            int i = t2 - 224;
            xt[(4 + (i >> 1)) * XT_COLS + ((i & 1) ? XT_COLS - 1 : 0)] = 0ull;
        }
    }
    __syncthreads();

    // ---- phase C: conv chunk 1
    if (isconv) need_c = chunk_hot(1);
    __syncthreads();

    // ---- phase D1 (cold): lazy full weight pack for flagged couts
#pragma unroll
    for (int i = 0; i < 4; ++i) {
        int cw = wid * 4 + i;
        if (needflag[cw]) {               // wave-uniform (same LDS word)
            const float* ws = w + (size_t)cw * (CIN * 9) + (size_t)lane * 9;
#pragma unroll
            for (int k = 0; k < 9; ++k) {
                uint64_t qb = __ballot(ws[k] > 0.0f);
                if (lane == 0) wsh[cw * 9 + k] = qb;
            }
        }
    }
    __syncthreads();

    // ---- phase D2 (cold): exact 9-tap equality eval for hit chunks
    if (need_b | need_c) {
        uint64_t wpA[9], wpB[9];
#pragma unroll
        for (int k = 0; k < 9; ++k) {
            wpA[k] = wsh[co0 * 9 + k];
            wpB[k] = wsh[(co0 + 1) * 9 + k];
        }
#pragma unroll
        for (int chunk = 0; chunk < 2; ++chunk) {
            bool nd = chunk ? need_c : need_b;
            if (!nd) continue;
            uint64_t rA[4][6];
#pragma unroll
            for (int r = 0; r < 4; ++r) {
                const ulonglong2* p =
                    (const ulonglong2*)&xt[(2 * chunk + r) * XT_COLS + c0];
                ulonglong2 a = p[0], b = p[1], cc = p[2];
                rA[r][0] = a.x; rA[r][1] = a.y; rA[r][2] = b.x;
                rA[r][3] = b.y; rA[r][4] = cc.x; rA[r][5] = cc.y;
            }
            float* obase = out + ((size_t)n * COUT + co0) * HW
                               + (size_t)(h0 + 2 * chunk) * WWD + c0;
#pragma unroll
            for (int ci = 0; ci < 2; ++ci) {
                int bb = ci ? bb1 : bb0;
                float* ob = obase + (size_t)ci * HW;
#pragma unroll
                for (int r = 0; r < 2; ++r) {
                    float v[4];
#pragma unroll
                    for (int o = 0; o < 4; ++o) {
                        int e = bb;
#pragma unroll
                        for (int kh = 0; kh < 3; ++kh)
#pragma unroll
                            for (int kw = 0; kw < 3; ++kw)
                                e &= (rA[r + kh][o + kw] ==
                                      (ci ? wpB[kh * 3 + kw] : wpA[kh * 3 + kw]));
                        v[o] = e ? 1.0f : 0.0f;
                    }
                    *(float4*)(ob + (size_t)r * WWD) =
                        make_float4(v[0], v[1], v[2], v[3]);
                }
            }
        }
    }
}

extern "C" void kernel_launch(void* const* d_in, const int* in_sizes, int n_in,
                              void* d_out, int out_size, void* d_ws, size_t ws_size,
                              hipStream_t stream) {
    const float* x    = (const float*)d_in[0];
    const float* wgt  = (const float*)d_in[1];
    const float* bias = (const float*)d_in[2];
    float* out = (float*)d_out;

    fused_conv<<<NBLOCKS, NTHREADS, 0, stream>>>(x, wgt, bias, out);
}

// Round 14
// 11.099 us; speedup vs baseline: 1.3099x; 1.0519x over previous
//
#include <hip/hip_runtime.h>
#include <stdint.h>

// FSUConv2d single-cycle bipolar forward == binary XNOR-conv with threshold:
//   per tap popc(x&w) + popc(~x&~w) = 64 - popc(x^w); zero-padded tile makes
//   pad taps follow the same formula. pc = 576 - S + b_bit, S = sum popc(x^w).
//   out = (pc >= 577) = (S == 0 && b_bit) = (all 9 tap words EQUAL && b_bit).
//
// Single dispatch, 224 blocks x 1024 threads, pipelined (R13) + LAZY HALO:
// the hot center-tap path reads only xt rows 1..4 = the block's OWN rows
// (out row r's center tap is xt row r+1), so the halo rows 0/5, the pad
// columns, and the full weight words are ALL packed lazily behind the
// needflag gate (P ~ 2^-64 per word on bitstream data). Machine-wide x
// reads drop 19.3 MB -> 12.8 MB (no halo redundancy).
//   A: pack xt rows 1..3 + center-tap weight words + bias flags.   [read]
//   B: tids 0..447 conv chunk 0 (reject -> zero stores)            [write]
//      tids 448..559 pack xt row 4 concurrently.                   [read]
//   C: conv chunk 1.                                               [write]
//   D: (cold) halo rows 0/5 + pad words + full weights -> exact eval.

#define NB   16
#define CIN  64
#define HH   56
#define WWD  56
#define COUT 64
#define HW   (HH * WWD)             // 3136
#define RPB  4
#define BANDS (HH / RPB)            // 14
#define NBLOCKS (NB * BANDS)        // 224
#define XT_COLS 58
#define NTHREADS 1024

__global__ __launch_bounds__(NTHREADS) void fused_conv(const float* __restrict__ x,
                                                       const float* __restrict__ w,
                                                       const float* __restrict__ bias,
                                                       float* __restrict__ out) {
    __shared__ uint64_t xt[6 * XT_COLS];
    __shared__ uint64_t wsh[COUT * 9];    // full weight words (lazy)
    __shared__ uint64_t wcen[COUT];       // center-tap words (hot)
    __shared__ int bflag[COUT];
    __shared__ int needflag[COUT];
    __shared__ int anyneed;

    int n    = blockIdx.x / BANDS;
    int band = blockIdx.x % BANDS;
    int h0   = band * RPB;
    int tid  = threadIdx.x;
    int wid  = tid >> 6;
    int lane = tid & 63;

    // pack one (xt-row, 8ch-group, 4px-quad) task; xt row r <- image row h0+r-1
    auto pack_task = [&](int row, int rem) {
        int cg8 = rem / 14;
        int pg  = rem - cg8 * 14;
        int gh  = h0 - 1 + row;
        int pc0 = pg * 4;
        uint32_t b0 = 0, b1 = 0, b2 = 0, b3 = 0;
        if (gh >= 0 && gh < HH) {         // always true for hot rows 1..4
            const float* xp = x + (size_t)n * CIN * HW + (size_t)(cg8 * 8) * HW
                                + (size_t)gh * WWD + pc0;
#pragma unroll
            for (int i = 0; i < 8; ++i) {
                float4 v = *(const float4*)(xp + (size_t)i * HW);
                b0 |= (uint32_t)(v.x != 0.0f) << i;
                b1 |= (uint32_t)(v.y != 0.0f) << i;
                b2 |= (uint32_t)(v.z != 0.0f) << i;
                b3 |= (uint32_t)(v.w != 0.0f) << i;
            }
        }
        uint8_t* xb = (uint8_t*)xt;
        int base = (row * XT_COLS + 1 + pc0) * 8 + cg8;
        xb[base]      = (uint8_t)b0;
        xb[base + 8]  = (uint8_t)b1;
        xb[base + 16] = (uint8_t)b2;
        xb[base + 24] = (uint8_t)b3;
    };

    // ---- phase A: pack own rows 1..3; wcen; flags
    if (tid < 336) pack_task(1 + tid / 112, tid % 112);
#pragma unroll
    for (int i = 0; i < 4; ++i) {
        int co = wid * 4 + i;
        float f = w[(size_t)co * (CIN * 9) + (size_t)lane * 9 + 4];
        uint64_t qb = __ballot(f > 0.0f);
        if (lane == 0) wcen[co] = qb;
    }
    if (tid < COUT) {
        bflag[tid]    = bias[tid] > 0.0f;
        needflag[tid] = 0;
    }
    if (tid == 0) anyneed = 0;
    __syncthreads();

    bool isconv = tid < 448;
    int c0 = 0, co0 = 0, bb0 = 0, bb1 = 0;
    uint64_t wc0 = 0, wc1 = 0;
    if (isconv) {
        int q  = tid % 14;
        int cp = tid / 14;
        c0  = q * 4;
        co0 = cp * 2;
        wc0 = wcen[co0];
        wc1 = wcen[co0 + 1];
        bb0 = bflag[co0];
        bb1 = bflag[co0 + 1];
    }

    // hot: center-tap reject for out rows h0+2*chunk, h0+2*chunk+1
    auto chunk_hot = [&](int chunk) -> bool {
        uint64_t rc2[2][6];
#pragma unroll
        for (int r = 0; r < 2; ++r) {
            const ulonglong2* p =
                (const ulonglong2*)&xt[(2 * chunk + 1 + r) * XT_COLS + c0];
            ulonglong2 a = p[0], b = p[1], cc = p[2];
            rc2[r][0] = a.x; rc2[r][1] = a.y; rc2[r][2] = b.x;
            rc2[r][3] = b.y; rc2[r][4] = cc.x; rc2[r][5] = cc.y;
        }
        int hit0 = 0, hit1 = 0;
#pragma unroll
        for (int r = 0; r < 2; ++r)
#pragma unroll
            for (int o = 0; o < 4; ++o) {
                uint64_t cw = rc2[r][o + 1];
                hit0 |= (cw == wc0);
                hit1 |= (cw == wc1);
            }
        bool need = ((hit0 & bb0) | (hit1 & bb1)) != 0;
        float* ob0 = out + ((size_t)n * COUT + co0) * HW
                         + (size_t)(h0 + 2 * chunk) * WWD + c0;
        if (need) {                       // benign races: only ever write 1
            needflag[co0]     = 1;
            needflag[co0 + 1] = 1;
            anyneed           = 1;
        } else {
            float4 z = make_float4(0.0f, 0.0f, 0.0f, 0.0f);
            *(float4*)ob0              = z;
            *(float4*)(ob0 + WWD)      = z;
            *(float4*)(ob0 + HW)       = z;
            *(float4*)(ob0 + HW + WWD) = z;
        }
        return need;
    };

    // ---- phase B: conv chunk 0 (stores) || pack own row 4 (reads)
    bool need_b = false, need_c = false;
    if (isconv) {
        need_b = chunk_hot(0);
    } else {
        int t2 = tid - 448;
        if (t2 < 112) pack_task(4, t2);
    }
    __syncthreads();

    // ---- phase C: conv chunk 1
    if (isconv) need_c = chunk_hot(1);
    __syncthreads();

    // ---- phase D1 (cold): halo rows 0/5, pad words, full weight words
    if (anyneed) {
        if (tid < 224) {
            pack_task(tid < 112 ? 0 : 5, tid % 112);
        } else if (tid < 236) {
            int i = tid - 224;            // 12 pad-column words, rows 0..5
            xt[(i >> 1) * XT_COLS + ((i & 1) ? XT_COLS - 1 : 0)] = 0ull;
        }
#pragma unroll
        for (int i = 0; i < 4; ++i) {
            int cw = wid * 4 + i;
            if (needflag[cw]) {           // wave-uniform (same LDS word)
                const float* ws = w + (size_t)cw * (CIN * 9) + (size_t)lane * 9;
#pragma unroll
                for (int k = 0; k < 9; ++k) {
                    uint64_t qb = __ballot(ws[k] > 0.0f);
                    if (lane == 0) wsh[cw * 9 + k] = qb;
                }
            }
        }
    }
    __syncthreads();

    // ---- phase D2 (cold): exact 9-tap equality eval for hit chunks
    if (need_b | need_c) {
        uint64_t wpA[9], wpB[9];
#pragma unroll
        for (int k = 0; k < 9; ++k) {
            wpA[k] = wsh[co0 * 9 + k];
            wpB[k] = wsh[(co0 + 1) * 9 + k];
        }
#pragma unroll
        for (int chunk = 0; chunk < 2; ++chunk) {
            bool nd = chunk ? need_c : need_b;
            if (!nd) continue;
            uint64_t rA[4][6];
#pragma unroll
            for (int r = 0; r < 4; ++r) {
#pragma unroll
                for (int c = 0; c < 6; ++c)
                    rA[r][c] = xt[(2 * chunk + r) * XT_COLS + c0 + c];
            }
            float* obase = out + ((size_t)n * COUT + co0) * HW
                               + (size_t)(h0 + 2 * chunk) * WWD + c0;
#pragma unroll
            for (int ci = 0; ci < 2; ++ci) {
                int bb = ci ? bb1 : bb0;
                float* ob = obase + (size_t)ci * HW;
#pragma unroll
                for (int r = 0; r < 2; ++r) {
                    float v[4];
#pragma unroll
                    for (int o = 0; o < 4; ++o) {
                        int e = bb;
#pragma unroll
                        for (int kh = 0; kh < 3; ++kh)
#pragma unroll
                            for (int kw = 0; kw < 3; ++kw)
                                e &= (rA[r + kh][o + kw] ==
                                      (ci ? wpB[kh * 3 + kw] : wpA[kh * 3 + kw]));
                        v[o] = e ? 1.0f : 0.0f;
                    }
                    *(float4*)(ob + (size_t)r * WWD) =
                        make_float4(v[0], v[1], v[2], v[3]);
                }
            }
        }
    }
}

extern "C" void kernel_launch(void* const* d_in, const int* in_sizes, int n_in,
                              void* d_out, int out_size, void* d_ws, size_t ws_size,
                              hipStream_t stream) {
    const float* x    = (const float*)d_in[0];
    const float* wgt  = (const float*)d_in[1];
    const float* bias = (const float*)d_in[2];
    float* out = (float*)d_out;

    fused_conv<<<NBLOCKS, NTHREADS, 0, stream>>>(x, wgt, bias, out);
}

// Round 15
// 11.029 us; speedup vs baseline: 1.3183x; 1.0064x over previous
//
#include <hip/hip_runtime.h>
#include <stdint.h>

// FSUConv2d single-cycle bipolar forward == binary XNOR-conv with threshold:
//   per tap popc(x&w) + popc(~x&~w) = 64 - popc(x^w); zero-padded tile makes
//   pad taps follow the same formula. pc = 576 - S + b_bit, S = sum popc(x^w).
//   out = (pc >= 577) = (S == 0 && b_bit) = (all 9 tap words EQUAL && b_bit).
//
// Single dispatch, 224 blocks x 1024 threads, pipelined (R13) + lazy halo
// (R14) + 32-CHANNEL HOT SLICE (new): the center-tap rejector only tests
// channels 0..31 (P(pass) = 2^-32 per word on random bitstreams), so the hot
// path packs only xt_lo (6.4 MB machine-wide x reads, half of R14) and reads
// only 18 weight lines/cout (74 KB/block, half). Channels 32..63 (xt_hi),
// halo rows, pad cols, and full 9-tap weight words are all packed lazily
// behind the anyneed gate; the exact 64-bit 9-tap eval still guarantees
// correctness for arbitrary (adversarial) inputs.
//   A: pack xt_lo rows 1..3 + wcen(ch0..31, 2 couts/wave-load) + flags.
//   B: tids 0..447 conv chunk 0 (u32 center reject -> zero stores)
//      tids 448..503 pack xt_lo row 4 concurrently.
//   C: conv chunk 1.
//   D: (cold) xt_hi all rows + xt_lo halo + pads + full weights -> exact.

#define NB   16
#define CIN  64
#define HH   56
#define WWD  56
#define COUT 64
#define HW   (HH * WWD)             // 3136
#define RPB  4
#define BANDS (HH / RPB)            // 14
#define NBLOCKS (NB * BANDS)        // 224
#define XT_STRIDE 60                // uint32 row stride; 240B = 16B-aligned rows
#define NTHREADS 1024

__global__ __launch_bounds__(NTHREADS) void fused_conv(const float* __restrict__ x,
                                                       const float* __restrict__ w,
                                                       const float* __restrict__ bias,
                                                       float* __restrict__ out) {
    __shared__ uint32_t xt_lo[6 * XT_STRIDE];   // channels 0..31 (hot)
    __shared__ uint32_t xt_hi[6 * XT_STRIDE];   // channels 32..63 (lazy)
    __shared__ uint64_t wsh[COUT * 9];          // full weight words (lazy)
    __shared__ uint32_t wcen[COUT];             // center-tap ch0..31 (hot)
    __shared__ int bflag[COUT];
    __shared__ int needflag[COUT];
    __shared__ int anyneed;

    int n    = blockIdx.x / BANDS;
    int band = blockIdx.x % BANDS;
    int h0   = band * RPB;
    int tid  = threadIdx.x;
    int wid  = tid >> 6;
    int lane = tid & 63;

    // pack one (xt row, 8ch-group cg in [0,4), 4px quad) task; ch = chbase+8cg+i
    auto pack_task = [&](uint32_t* xtbuf, int chbase, int row, int rem) {
        int cg  = rem / 14;
        int pg  = rem - cg * 14;
        int gh  = h0 - 1 + row;
        int pc0 = pg * 4;
        uint32_t b0 = 0, b1 = 0, b2 = 0, b3 = 0;
        if (gh >= 0 && gh < HH) {
            const float* xp = x + (size_t)n * CIN * HW + (size_t)(chbase + cg * 8) * HW
                                + (size_t)gh * WWD + pc0;
#pragma unroll
            for (int i = 0; i < 8; ++i) {
                float4 v = *(const float4*)(xp + (size_t)i * HW);
                b0 |= (uint32_t)(v.x != 0.0f) << i;
                b1 |= (uint32_t)(v.y != 0.0f) << i;
                b2 |= (uint32_t)(v.z != 0.0f) << i;
                b3 |= (uint32_t)(v.w != 0.0f) << i;
            }
        }
        uint8_t* xb = (uint8_t*)xtbuf;
        int base = (row * XT_STRIDE + 1 + pc0) * 4 + cg;
        xb[base]      = (uint8_t)b0;
        xb[base + 4]  = (uint8_t)b1;
        xb[base + 8]  = (uint8_t)b2;
        xb[base + 12] = (uint8_t)b3;
    };

    // ---- phase A: pack xt_lo rows 1..3; wcen (2 couts per wave-load); flags
    if (tid < 168) pack_task(xt_lo, 0, 1 + tid / 56, tid % 56);
#pragma unroll
    for (int j = 0; j < 2; ++j) {
        int co = wid * 4 + 2 * j + (lane >> 5);
        int c  = lane & 31;
        float f = w[(size_t)co * (CIN * 9) + (size_t)c * 9 + 4];
        uint64_t qb = __ballot(f > 0.0f);
        if (lane == 0) {
            wcen[wid * 4 + 2 * j]     = (uint32_t)qb;
            wcen[wid * 4 + 2 * j + 1] = (uint32_t)(qb >> 32);
        }
    }
    if (tid < COUT) {
        bflag[tid]    = bias[tid] > 0.0f;
        needflag[tid] = 0;
    }
    if (tid == 0) anyneed = 0;
    __syncthreads();

    bool isconv = tid < 448;
    int c0 = 0, co0 = 0, bb0 = 0, bb1 = 0;
    uint32_t wc0 = 0, wc1 = 0;
    if (isconv) {
        int q  = tid % 14;
        int cp = tid / 14;
        c0  = q * 4;
        co0 = cp * 2;
        wc0 = wcen[co0];
        wc1 = wcen[co0 + 1];
        bb0 = bflag[co0];
        bb1 = bflag[co0 + 1];
    }

    // hot: 32-bit center-tap reject for out rows h0+2*chunk, h0+2*chunk+1
    auto chunk_hot = [&](int chunk) -> bool {
        uint32_t rc[2][6];
#pragma unroll
        for (int r = 0; r < 2; ++r) {
            const uint32_t* base = &xt_lo[(2 * chunk + 1 + r) * XT_STRIDE + c0];
            uint4 a = *(const uint4*)base;       // 16B-aligned: stride 240, c0=4q
            uint2 b = *(const uint2*)(base + 4);
            rc[r][0] = a.x; rc[r][1] = a.y; rc[r][2] = a.z;
            rc[r][3] = a.w; rc[r][4] = b.x; rc[r][5] = b.y;
        }
        int hit0 = 0, hit1 = 0;
#pragma unroll
        for (int r = 0; r < 2; ++r)
#pragma unroll
            for (int o = 0; o < 4; ++o) {
                uint32_t cw = rc[r][o + 1];
                hit0 |= (cw == wc0);
                hit1 |= (cw == wc1);
            }
        bool need = ((hit0 & bb0) | (hit1 & bb1)) != 0;
        float* ob0 = out + ((size_t)n * COUT + co0) * HW
                         + (size_t)(h0 + 2 * chunk) * WWD + c0;
        if (need) {                       // benign races: only ever write 1
            needflag[co0]     = 1;
            needflag[co0 + 1] = 1;
            anyneed           = 1;
        } else {
            float4 z = make_float4(0.0f, 0.0f, 0.0f, 0.0f);
            *(float4*)ob0              = z;
            *(float4*)(ob0 + WWD)      = z;
            *(float4*)(ob0 + HW)       = z;
            *(float4*)(ob0 + HW + WWD) = z;
        }
        return need;
    };

    // ---- phase B: conv chunk 0 (stores) || pack xt_lo row 4 (reads)
    bool need_b = false, need_c = false;
    if (isconv) {
        need_b = chunk_hot(0);
    } else {
        int t2 = tid - 448;
        if (t2 < 56) pack_task(xt_lo, 0, 4, t2);
    }
    __syncthreads();

    // ---- phase C: conv chunk 1
    if (isconv) need_c = chunk_hot(1);
    __syncthreads();

    // ---- phase D1 (cold): xt_hi rows 0..5, xt_lo halo rows 0/5, pads, weights
    if (anyneed) {
        if (tid < 336) {
            pack_task(xt_hi, 32, tid / 56, tid % 56);
        } else if (tid < 448) {
            int t2 = tid - 336;
            pack_task(xt_lo, 0, (t2 < 56) ? 0 : 5, t2 % 56);
        } else if (tid < 472) {
            int i  = tid - 448;               // 24 pad-column words
            uint32_t* buf = (i < 12) ? xt_lo : xt_hi;
            int ii = i % 12;
            buf[(ii >> 1) * XT_STRIDE + ((ii & 1) ? 57 : 0)] = 0u;
        }
#pragma unroll
        for (int i = 0; i < 4; ++i) {
            int cw = wid * 4 + i;
            if (needflag[cw]) {               // wave-uniform (same LDS word)
                const float* ws = w + (size_t)cw * (CIN * 9) + (size_t)lane * 9;
#pragma unroll
                for (int k = 0; k < 9; ++k) {
                    uint64_t qb = __ballot(ws[k] > 0.0f);
                    if (lane == 0) wsh[cw * 9 + k] = qb;
                }
            }
        }
    }
    __syncthreads();

    // ---- phase D2 (cold): exact 64-bit 9-tap equality eval for hit chunks
    if (need_b | need_c) {
        uint64_t wpA[9], wpB[9];
#pragma unroll
        for (int k = 0; k < 9; ++k) {
            wpA[k] = wsh[co0 * 9 + k];
            wpB[k] = wsh[(co0 + 1) * 9 + k];
        }
#pragma unroll
        for (int chunk = 0; chunk < 2; ++chunk) {
            bool nd = chunk ? need_c : need_b;
            if (!nd) continue;
            uint64_t rA[4][6];
#pragma unroll
            for (int r = 0; r < 4; ++r)
#pragma unroll
                for (int c = 0; c < 6; ++c) {
                    int idx = (2 * chunk + r) * XT_STRIDE + c0 + c;
                    rA[r][c] = (uint64_t)xt_lo[idx] | ((uint64_t)xt_hi[idx] << 32);
                }
            float* obase = out + ((size_t)n * COUT + co0) * HW
                               + (size_t)(h0 + 2 * chunk) * WWD + c0;
#pragma unroll
            for (int ci = 0; ci < 2; ++ci) {
                int bb = ci ? bb1 : bb0;
                float* ob = obase + (size_t)ci * HW;
#pragma unroll
                for (int r = 0; r < 2; ++r) {
                    float v[4];
#pragma unroll
                    for (int o = 0; o < 4; ++o) {
                        int e = bb;
#pragma unroll
                        for (int kh = 0; kh < 3; ++kh)
#pragma unroll
                            for (int kw = 0; kw < 3; ++kw)
                                e &= (rA[r + kh][o + kw] ==
                                      (ci ? wpB[kh * 3 + kw] : wpA[kh * 3 + kw]));
                        v[o] = e ? 1.0f : 0.0f;
                    }
                    *(float4*)(ob + (size_t)r * WWD) =
                        make_float4(v[0], v[1], v[2], v[3]);
                }
            }
        }
    }
}

extern "C" void kernel_launch(void* const* d_in, const int* in_sizes, int n_in,
                              void* d_out, int out_size, void* d_ws, size_t ws_size,
                              hipStream_t stream) {
    const float* x    = (const float*)d_in[0];
    const float* wgt  = (const float*)d_in[1];
    const float* bias = (const float*)d_in[2];
    float* out = (float*)d_out;

    fused_conv<<<NBLOCKS, NTHREADS, 0, stream>>>(x, wgt, bias, out);
}